// Round 6
// baseline (290.396 us; speedup 1.0000x reference)
//
#include <hip/hip_runtime.h>
#include <hip/hip_fp16.h>
#include <stdint.h>

// LRU single-step collapsed:  y = u @ M^T + y0
//   M  = 2*(C_re G B_re - C_im G B_im) + D,  y0 = 2*(C_re c_re - C_im c_im), c = lam*x
// f16 MFMA, scaled hi/lo splits (x256 keeps lo-parts f16-normal).
// M-build: 128^2-tile split-K x8, 2-product (C_hi * (Bh+Bl)), fp32 atomicAdd partials.
// Main: 128^2 m97-structure, 2-product (u_hi(RTN) * (Mh+Ml)), epilogue /256 + y0.

typedef _Float16 f16x8 __attribute__((ext_vector_type(8)));
typedef float f32x4 __attribute__((ext_vector_type(4)));

#define GLOBAL_AS __attribute__((address_space(1)))
#define LDS_AS __attribute__((address_space(3)))

constexpr int BATCH = 16384, DIN = 1024, DSTATE = 2048, DOUT = 1024;
constexpr int S2 = 2 * DSTATE;  // 4096
constexpr int KSPLIT = 8;       // M-build split-K chunks

// Rows are 32 f16 = 64B = 4 x 16B slots; XOR-swizzle slot by ((row>>1)&3).
// Verified: SQ_LDS_BANK_CONFLICT == 0 (R1/R3).
__device__ __forceinline__ int lds_off(int row, int k) {
  int slot = k >> 3;
  int sl = slot ^ ((row >> 1) & 3);
  return row * 64 + sl * 16 + (k & 7) * 2;
}

// ---------------- Bgt[i][s2] = 256*exp(ga[s])*B[s][i], transposed, f16 hi/lo ----------------
__global__ void k_bgt(const float* __restrict__ Bre, const float* __restrict__ Bim,
                      const float* __restrict__ ga, __half* __restrict__ Bh,
                      __half* __restrict__ Bl) {
  __shared__ float tile[32][33];
  int s0 = blockIdx.x * 32, i0 = blockIdx.y * 32;
  int c = threadIdx.x & 31, r0 = threadIdx.x >> 5;  // 8 rows per pass
  const float* src = (s0 < DSTATE) ? Bre : Bim;
  int sbase = (s0 < DSTATE) ? s0 : s0 - DSTATE;
  for (int rr = 0; rr < 32; rr += 8) {
    int s = sbase + r0 + rr;
    tile[r0 + rr][c] = src[(long)s * DIN + i0 + c] * (256.f * expf(ga[s]));
  }
  __syncthreads();
  for (int rr = 0; rr < 32; rr += 8) {
    int i = i0 + r0 + rr;
    float v = tile[c][r0 + rr];
    __half h = __float2half(v);
    __half l = __float2half(v - __half2float(h));
    Bh[(long)i * S2 + s0 + c] = h;
    Bl[(long)i * S2 + s0 + c] = l;
  }
}

// ---------------- y0[j] = 2*sum_s (cre*C_re[j,s] - cim*C_im[j,s]), state inline ----------------
__global__ void k_y0(const float* __restrict__ xr, const float* __restrict__ xi,
                     const float* __restrict__ nu, const float* __restrict__ th,
                     const float* __restrict__ Cre, const float* __restrict__ Cim,
                     float* __restrict__ y0) {
  int j = blockIdx.x;
  float acc = 0.f;
  for (int s = threadIdx.x; s < DSTATE; s += 256) {
    float lm = expf(-expf(nu[s]));
    float t = expf(th[s]);
    float lr = lm * cosf(t), li = lm * sinf(t);
    float cr = lr * xr[s] - li * xi[s];
    float ci = lr * xi[s] + li * xr[s];
    acc += cr * Cre[(long)j * DSTATE + s] - ci * Cim[(long)j * DSTATE + s];
  }
  for (int off = 32; off; off >>= 1) acc += __shfl_down(acc, off);
  __shared__ float red[4];
  if ((threadIdx.x & 63) == 0) red[threadIdx.x >> 6] = acc;
  __syncthreads();
  if (threadIdx.x == 0) y0[j] = 2.f * (red[0] + red[1] + red[2] + red[3]);
}

// ---------------- GEMM: out[M][N] = A[M][K] @ B^T[N][K] ----------------
// AMODE 1: A = 512*[Cre|-Cim] (dual source, hi-only RTN).  AMODE 2: A = u fp32 (hi-only RTN).
// EPI 0: atomicAdd fp32 partial into outF.  EPI 1: y = acc/256 + y0[col].
template <int BM, int BN, int AMODE, int EPI>
__global__ __launch_bounds__(256, 2) void k_gemm(
    const float* __restrict__ A, const float* __restrict__ A2,
    const __half* __restrict__ Bh, const __half* __restrict__ Bl,
    const float* __restrict__ extra, float* __restrict__ outF,
    int M, int N, int K, int kiters) {
  constexpr int FM = BM / 32;
  constexpr int FN = BN / 32;
  constexpr int ABYTES = BM * 64;
  constexpr int BBYTES = BN * 64;
  __shared__ alignas(16) char smem[ABYTES + 2 * BBYTES];
  char* sA = smem;
  char* sBh = smem + ABYTES;
  char* sBl = smem + ABYTES + BBYTES;

  const int tid = threadIdx.x;
  const int lane = tid & 63;
  const int wid = tid >> 6;
  const int wr = wid >> 1, wc = wid & 1;
  int bm0, bn0, kb;
  if constexpr (EPI == 1) {
    // XCD-aware swizzle: grid 1024 (divisible by 8 -> bijective).
    int wg = blockIdx.x;
    int lin = (wg & 7) * 128 + (wg >> 3);
    bm0 = (lin >> 3) * BM;
    bn0 = (lin & 7) * BN;
    kb = 0;
  } else {
    bm0 = blockIdx.y * BM;
    bn0 = blockIdx.x * BN;
    kb = blockIdx.z * (S2 / KSPLIT);
  }
  const int r16 = lane & 15;
  const int ksl = lane >> 4;

  f32x4 acc[FM][FN];
#pragma unroll
  for (int i = 0; i < FM; ++i)
#pragma unroll
    for (int j = 0; j < FN; ++j) acc[i][j] = f32x4{0.f, 0.f, 0.f, 0.f};

  constexpr int APT = (BM * 8) / 256;  // f32x4 loads per thread for A tile
  constexpr int IPW = (BN / 16) / 4;   // global_load_lds insts per wave per buffer

  for (int kt = 0; kt < kiters; ++kt) {
    __syncthreads();
    // ---- stage A: fp32 -> f16 hi (RTN), swizzled ds_write ----
#pragma unroll
    for (int it = 0; it < APT; ++it) {
      int idx = it * 256 + tid;
      int row = idx >> 3;
      int k0 = (idx & 7) * 4;
      f32x4 v;
      if constexpr (AMODE == 2) {
        v = *(const f32x4*)(A + (long)(bm0 + row) * K + kb + kt * 32 + k0);
      } else {
        int s = kb + kt * 32 + k0;  // chunk never straddles DSTATE
        const float* src = (s < DSTATE) ? A : A2;
        int sc = (s < DSTATE) ? s : s - DSTATE;
        v = *(const f32x4*)(src + (long)(bm0 + row) * DSTATE + sc);
        v *= (s < DSTATE) ? 512.f : -512.f;  // 2*scale(256), sign folds the minus
      }
      union { __half h[4]; uint64_t u; } p;
#pragma unroll
      for (int j = 0; j < 4; ++j) p.h[j] = __float2half(v[j]);
      *(uint64_t*)(sA + lds_off(row, k0)) = p.u;
    }
    // ---- stage B via global_load_lds (linear dest, inverse-swizzled source) ----
#pragma unroll
    for (int ii = 0; ii < IPW; ++ii) {
      int inst = wid * IPW + ii;
      int row = inst * 16 + (lane >> 2);
      int slot = (lane & 3) ^ ((row >> 1) & 3);
      const __half* gh = Bh + (long)(bn0 + row) * K + kb + kt * 32 + slot * 8;
      const __half* gl = Bl + (long)(bn0 + row) * K + kb + kt * 32 + slot * 8;
      __builtin_amdgcn_global_load_lds((GLOBAL_AS const unsigned int*)gh,
                                       (LDS_AS unsigned int*)(sBh + inst * 1024), 16, 0, 0);
      __builtin_amdgcn_global_load_lds((GLOBAL_AS const unsigned int*)gl,
                                       (LDS_AS unsigned int*)(sBl + inst * 1024), 16, 0, 0);
    }
    __syncthreads();
    // ---- compute: 2-product (a * bh + a * bl) ----
    f16x8 a[FM], bh[FN], bl[FN];
#pragma unroll
    for (int m = 0; m < FM; ++m) {
      int row = wr * (BM / 2) + m * 16 + r16;
      a[m] = *(const f16x8*)(sA + lds_off(row, ksl * 8));
    }
#pragma unroll
    for (int n = 0; n < FN; ++n) {
      int row = wc * (BN / 2) + n * 16 + r16;
      bh[n] = *(const f16x8*)(sBh + lds_off(row, ksl * 8));
      bl[n] = *(const f16x8*)(sBl + lds_off(row, ksl * 8));
    }
#pragma unroll
    for (int m = 0; m < FM; ++m)
#pragma unroll
      for (int n = 0; n < FN; ++n)
        acc[m][n] = __builtin_amdgcn_mfma_f32_16x16x32_f16(a[m], bh[n], acc[m][n], 0, 0, 0);
#pragma unroll
    for (int m = 0; m < FM; ++m)
#pragma unroll
      for (int n = 0; n < FN; ++n)
        acc[m][n] = __builtin_amdgcn_mfma_f32_16x16x32_f16(a[m], bl[n], acc[m][n], 0, 0, 0);
  }

  // ---- epilogue (C/D layout: col = lane&15, row = (lane>>4)*4 + reg) ----
  const int rowb = (lane >> 4) * 4;
#pragma unroll
  for (int m = 0; m < FM; ++m)
#pragma unroll
    for (int n = 0; n < FN; ++n)
#pragma unroll
      for (int r = 0; r < 4; ++r) {
        int gr = bm0 + wr * (BM / 2) + m * 16 + rowb + r;
        int gc = bn0 + wc * (BN / 2) + n * 16 + r16;
        if constexpr (EPI == 0) {
          atomicAdd(outF + (long)gr * N + gc, acc[m][n][r]);
        } else {
          outF[(long)gr * N + gc] = acc[m][n][r] * (1.f / 256.f) + extra[gc];
        }
      }
}

// ---------------- M = Mpart/65536/... -> store 256*M hi/lo ----------------
// Mpart holds 65536*(M - D); v = Mpart/256 + 256*D = 256*M.
__global__ void k_redM(const float* __restrict__ P, const float* __restrict__ D,
                       __half* __restrict__ Mh, __half* __restrict__ Ml) {
  int idx = (blockIdx.x * 256 + threadIdx.x) * 4;
  f32x4 s = *(const f32x4*)(P + idx);
  f32x4 d = *(const f32x4*)(D + idx);
  union { __half h[4]; uint64_t u; } ph, pl;
#pragma unroll
  for (int j = 0; j < 4; ++j) {
    float v = s[j] * (1.f / 256.f) + 256.f * d[j];
    __half hh = __float2half(v);
    ph.h[j] = hh;
    pl.h[j] = __float2half(v - __half2float(hh));
  }
  *(uint64_t*)(Mh + idx) = ph.u;
  *(uint64_t*)(Ml + idx) = pl.u;
}

extern "C" void kernel_launch(void* const* d_in, const int* in_sizes, int n_in,
                              void* d_out, int out_size, void* d_ws, size_t ws_size,
                              hipStream_t stream) {
  const float* u   = (const float*)d_in[0];
  const float* xr  = (const float*)d_in[1];
  const float* xi  = (const float*)d_in[2];
  const float* nu  = (const float*)d_in[3];
  const float* th  = (const float*)d_in[4];
  const float* ga  = (const float*)d_in[5];
  const float* Bre = (const float*)d_in[6];
  const float* Bim = (const float*)d_in[7];
  const float* Cre = (const float*)d_in[8];
  const float* Cim = (const float*)d_in[9];
  const float* Dm  = (const float*)d_in[10];
  float* y = (float*)d_out;

  char* w = (char*)d_ws;
  float* y0  = (float*)(w);                                  // 4 KB
  __half* Bgh = (__half*)(w + 65536);                        // [DIN][S2] 8 MB
  __half* Bgl = (__half*)(w + 65536 + 8388608);              // 8 MB
  __half* Mh  = (__half*)(w + 65536 + 16777216);             // 2 MB
  __half* Ml  = (__half*)(w + 65536 + 16777216 + 2097152);   // 2 MB
  float* Mpart = (float*)(w + 65536 + 16777216 + 4194304);   // 4 MB
  // total ws use ~25.2 MB

  hipMemsetAsync(Mpart, 0, (size_t)DOUT * DIN * 4, stream);
  k_bgt<<<dim3(S2 / 32, DIN / 32), 256, 0, stream>>>(Bre, Bim, ga, Bgh, Bgl);
  k_y0<<<DOUT, 256, 0, stream>>>(xr, xi, nu, th, Cre, Cim, y0);
  // M-build: 128^2 tile, split-K x8, atomic fp32 accumulate
  k_gemm<128, 128, 1, 0><<<dim3(DIN / 128, DOUT / 128, KSPLIT), 256, 0, stream>>>(
      Cre, Cim, Bgh, Bgl, nullptr, Mpart, DOUT, DIN, S2, (S2 / KSPLIT) / 32);
  k_redM<<<1024, 256, 0, stream>>>(Mpart, Dm, Mh, Ml);
  // main: y[b][j] = (sum_i u_hi[b][i] * 256M[j][i])/256 + y0[j]
  k_gemm<128, 128, 2, 1><<<(BATCH / 128) * (DOUT / 128), 256, 0, stream>>>(
      u, nullptr, Mh, Ml, y0, y, BATCH, DOUT, DIN, DIN / 32);
}